// Round 13
// baseline (135.554 us; speedup 1.0000x reference)
//
#include <hip/hip_runtime.h>
#include <hip/hip_bf16.h>

#define NN 8192
#define FF 128
#define BM 64
#define BK 64
#define KS 8
#define KCH (NN / KS)      // 1024 K per block
#define NSTEP (KCH / BK)   // 16

typedef __attribute__((ext_vector_type(8))) short bf16x8;   // 8 bf16 (4 VGPR)
typedef __attribute__((ext_vector_type(4))) float f32x4;

__device__ __forceinline__ short f2bf(float f) {
  unsigned u = __float_as_uint(f);
  u += 0x7FFFu + ((u >> 16) & 1u);
  return (short)(u >> 16);
}
__device__ __forceinline__ float bf2f(short s) {
  return __uint_as_float(((unsigned)(unsigned short)s) << 16);
}

// async global->LDS DMA, 16B per lane. Dest = wave-uniform LDS base + lane*16.
// Consumes NO VGPRs -> the compiler cannot sink it (R9/R10: reg prefetch
// always got sunk/spilled). Increments vmcnt; completion = LDS written.
__device__ __forceinline__ void dma16(const void* g, void* lds) {
  __builtin_amdgcn_global_load_lds(
      (const __attribute__((address_space(1))) unsigned int*)(uintptr_t)g,
      (__attribute__((address_space(3))) unsigned int*)(lds),
      16, 0, 0);
}

// packed f32x2 -> bf16x2 (RNE, same results as f2bf), 4 inst per 8 floats
__device__ __forceinline__ bf16x8 cvt8(float4 lo, float4 hi) {
  union { bf16x8 v; unsigned u[4]; } r;
  asm("v_cvt_pk_bf16_f32 %0, %1, %2" : "=v"(r.u[0]) : "v"(lo.x), "v"(lo.y));
  asm("v_cvt_pk_bf16_f32 %0, %1, %2" : "=v"(r.u[1]) : "v"(lo.z), "v"(lo.w));
  asm("v_cvt_pk_bf16_f32 %0, %1, %2" : "=v"(r.u[2]) : "v"(hi.x), "v"(hi.y));
  asm("v_cvt_pk_bf16_f32 %0, %1, %2" : "=v"(r.u[3]) : "v"(hi.z), "v"(hi.w));
  return r.v;
}

// ---- kernel 1: deg[i] = rowsum(adj)+1 ; dinv[i] = (deg+1e-8)^-0.5 ----
__global__ __launch_bounds__(256) void k_deg(const float* __restrict__ adj,
                                             float* __restrict__ dinv) {
  const int row = blockIdx.x;
  const float4* p = (const float4*)(adj + (size_t)row * NN);
  float s = 0.f;
#pragma unroll
  for (int it = 0; it < 8; ++it) {
    float4 v = p[it * 256 + threadIdx.x];
    s += (v.x + v.y) + (v.z + v.w);
  }
#pragma unroll
  for (int off = 32; off > 0; off >>= 1) s += __shfl_down(s, off, 64);
  __shared__ float partial[4];
  if ((threadIdx.x & 63) == 0) partial[threadIdx.x >> 6] = s;
  __syncthreads();
  if (threadIdx.x == 0) {
    float deg = (partial[0] + partial[1]) + (partial[2] + partial[3]) + 1.0f;
    dinv[row] = 1.0f / sqrtf(deg + 1e-8f);
  }
}

// ---- kernel 2: yT[f][i] = dinv[i] * x[i][f]  (bf16, transposed for NT GEMM) ----
__global__ __launch_bounds__(256) void k_scale_t(const float* __restrict__ x,
                                                 const float* __restrict__ dinv,
                                                 short* __restrict__ yT) {
  __shared__ float tile[64][129];
  const int r0 = blockIdx.x * 64;
  const int tid = threadIdx.x;
#pragma unroll
  for (int it = 0; it < 8; ++it) {
    int q = it * 256 + tid;
    int r = q >> 5;
    int c = q & 31;
    float4 v = ((const float4*)(x + (size_t)(r0 + r) * FF))[c];
    float d = dinv[r0 + r];
    tile[r][c * 4 + 0] = v.x * d;
    tile[r][c * 4 + 1] = v.y * d;
    tile[r][c * 4 + 2] = v.z * d;
    tile[r][c * 4 + 3] = v.w * d;
  }
  __syncthreads();
  const int f = tid >> 1;
  const int i0 = (tid & 1) * 32;
#pragma unroll
  for (int g = 0; g < 4; ++g) {
    bf16x8 o;
#pragma unroll
    for (int j = 0; j < 8; ++j) o[j] = f2bf(tile[i0 + g * 8 + j][f]);
    *(bf16x8*)(yT + (size_t)f * NN + r0 + i0 + g * 8) = o;
  }
}

// ---- kernel 3: zpart[ks] = adj[:, ksliced] @ y. DMA-ring MFMA GEMM (T3/T4). ----
// 1024 blocks (128 M-tiles x 8 K-slices), 512 thr = 8 waves (2M x 4N),
// BM=64, BN=128(all), BK=64. FOUR-buffer LDS ring (128 KB): tile t+3's DMA
// issues at end of phase t, consumed at phase t+3 (~2.5 phases > HBM latency).
// Counted vmcnt(8) per phase — NEVER drains to 0 in the main loop (T4);
// 12 DMA-instr/wave in flight = 96 KB/CU (Little's law needs ~10 KB).
// WAR on ring slot: slot (t+3)&3 last read at phase t-1, sealed by that
// phase's lgkmcnt(0)+barrier. Staging/cvt/swizzle identical to the proven
// R12 kernel (absmax bit-identical).
__global__ __launch_bounds__(512) void k_gemm(const float* __restrict__ adj,
                                              const short* __restrict__ yT,
                                              short* __restrict__ zpart) {
  __shared__ float Asf[4][BM * BK];        // 4 x 16 KB, f32, swizzled chunks
  __shared__ short Bsf[4][128 * BK];       // 4 x 16 KB, bf16, swizzled chunks
  const int tid = threadIdx.x;
  const int wave = tid >> 6;
  const int lane = tid & 63;
  const int mb = 127 - (int)(blockIdx.x & 127);   // reverse: read L3-warm rows first
  const int ks = blockIdx.x >> 7;
  const int row0 = mb * BM;
  const size_t kbase = (size_t)ks * KCH;

  // --- DMA source map (inverse-swizzled so linear LDS dest ends up swizzled).
  const int rowA = tid >> 4;                       // 0..31
  const int c4l  = (tid & 15) ^ (rowA & 7);
  const float* pa0 = adj + (size_t)(row0 + rowA) * NN + kbase + c4l * 4;
  const float* pa1 = pa0 + (size_t)32 * NN;        // rows +32
  const int rowB = tid >> 3;                       // 0..63
  const int c8l  = (tid & 7) ^ (rowB & 7);
  const short* pb0 = yT + (size_t)rowB * NN + kbase + c8l * 8;
  const short* pb1 = pb0 + (size_t)64 * NN;        // rows +64

  const int ldsOff = wave * 1024;                  // wave's chunk window (bytes)

#define STAGE_DMA(BUF, koff) do {                                              \
    char* la = (char*)&Asf[BUF][0] + ldsOff;                                   \
    char* lb = (char*)&Bsf[BUF][0] + ldsOff;                                   \
    dma16(pa0 + (koff), la);                                                   \
    dma16(pa1 + (koff), la + 8192);                                            \
    dma16(pb0 + (koff), lb);                                                   \
    dma16(pb1 + (koff), lb + 8192);                                            \
  } while (0)

  // --- compute-side fragment map (proven MFMA layout, swizzled addresses)
  const int wm = (wave >> 2) * 32;   // 0/32
  const int wn = (wave & 3) * 32;    // 0/32/64/96
  const int fr = lane & 15;
  const int kh = (lane >> 4) * 8;
  const int khq = kh >> 2;           // A chunk sub-offset (f32 16B chunks)
  const int kh8 = kh >> 3;           // B chunk sub-offset
  const int sw  = fr & 7;            // row swizzle (wm/wn/16 are 0 mod 8)
  const int ra0 = wm + fr, ra1 = ra0 + 16;
  const int rb0 = wn + fr, rb1 = rb0 + 16;

  f32x4 acc00 = {0.f,0.f,0.f,0.f}, acc01 = acc00, acc10 = acc00, acc11 = acc00;

#define COMPUTE(BUF) do {                                                      \
    const char* Ab = (const char*)&Asf[BUF][0];                                \
    const char* Bb = (const char*)&Bsf[BUF][0];                                \
    _Pragma("unroll")                                                          \
    for (int kk = 0; kk < 2; ++kk) {                                           \
      int c4 = kk * 8 + khq;                                                   \
      int c8 = kk * 4 + kh8;                                                   \
      float4 lo0 = *(const float4*)(Ab + ra0 * 256 + (((c4    ) ^ sw) << 4));  \
      float4 hi0 = *(const float4*)(Ab + ra0 * 256 + (((c4 + 1) ^ sw) << 4));  \
      float4 lo1 = *(const float4*)(Ab + ra1 * 256 + (((c4    ) ^ sw) << 4));  \
      float4 hi1 = *(const float4*)(Ab + ra1 * 256 + (((c4 + 1) ^ sw) << 4));  \
      bf16x8 b0 = *(const bf16x8*)(Bb + rb0 * 128 + ((c8 ^ sw) << 4));         \
      bf16x8 b1 = *(const bf16x8*)(Bb + rb1 * 128 + ((c8 ^ sw) << 4));         \
      bf16x8 a0 = cvt8(lo0, hi0);                                              \
      bf16x8 a1 = cvt8(lo1, hi1);                                              \
      acc00 = __builtin_amdgcn_mfma_f32_16x16x32_bf16(a0, b0, acc00, 0, 0, 0); \
      acc01 = __builtin_amdgcn_mfma_f32_16x16x32_bf16(a0, b1, acc01, 0, 0, 0); \
      acc10 = __builtin_amdgcn_mfma_f32_16x16x32_bf16(a1, b0, acc10, 0, 0, 0); \
      acc11 = __builtin_amdgcn_mfma_f32_16x16x32_bf16(a1, b1, acc11, 0, 0, 0); \
    }                                                                          \
  } while (0)

  // prologue: stage tiles 0,1,2 into ring slots 0,1,2 (12 DMAs in flight)
  STAGE_DMA(0, 0);
  STAGE_DMA(1, BK);
  STAGE_DMA(2, 2 * BK);

  for (int t = 0; t < NSTEP; ++t) {
    const int ahead = NSTEP - 1 - t;     // staged tiles beyond t
    if (ahead >= 2)      asm volatile("s_waitcnt vmcnt(8)" ::: "memory");
    else if (ahead == 1) asm volatile("s_waitcnt vmcnt(4)" ::: "memory");
    else                 asm volatile("s_waitcnt vmcnt(0)" ::: "memory");
    __builtin_amdgcn_s_barrier();        // all waves' tile-t DMAs landed
    __builtin_amdgcn_sched_barrier(0);
    COMPUTE(t & 3);
    asm volatile("s_waitcnt lgkmcnt(0)" ::: "memory");
    __builtin_amdgcn_s_barrier();        // all waves done reading slot t&3
    __builtin_amdgcn_sched_barrier(0);
    if (t + 3 < NSTEP) STAGE_DMA((t + 3) & 3, (t + 3) * BK);
  }

  // epilogue: D layout col=lane&15, row=(lane>>4)*4+r ; store bf16 partials
  const int r4 = (lane >> 4) * 4;
  short* zp = zpart + ((size_t)ks << 20);   // slice stride 8192*128
#pragma unroll
  for (int r = 0; r < 4; ++r) {
    int gi0 = row0 + wm + r4 + r;
    int gi1 = gi0 + 16;
    zp[(size_t)gi0 * FF + wn + fr]      = f2bf(acc00[r]);
    zp[(size_t)gi0 * FF + wn + 16 + fr] = f2bf(acc01[r]);
    zp[(size_t)gi1 * FF + wn + fr]      = f2bf(acc10[r]);
    zp[(size_t)gi1 * FF + wn + 16 + fr] = f2bf(acc11[r]);
  }
#undef STAGE_DMA
#undef COMPUTE
}

// ---- kernel 4: out = relu((dinv*(sum_ks zpart + dinv*x)) @ W) ----
__global__ __launch_bounds__(256) void k_out(const short* __restrict__ zpart,
                                             const float* __restrict__ x,
                                             const float* __restrict__ dinv,
                                             const float* __restrict__ w,
                                             float* __restrict__ out) {
  __shared__ float zs[16][128];
  const int r0 = blockIdx.x * 16;
  const int tid = threadIdx.x;
#pragma unroll
  for (int half = 0; half < 2; ++half) {
    int p = half * 256 + tid;
    int r = p >> 5;
    int c4 = p & 31;
    int gi = r0 + r;
    const short* base = zpart + (size_t)gi * FF + c4 * 4;
    float s0 = 0.f, s1 = 0.f, s2 = 0.f, s3 = 0.f;
#pragma unroll
    for (int sidx = 0; sidx < KS; ++sidx) {
      short4 v = *(const short4*)(base + ((size_t)sidx << 20));
      s0 += bf2f(v.x); s1 += bf2f(v.y); s2 += bf2f(v.z); s3 += bf2f(v.w);
    }
    float4 xv = *(const float4*)(x + (size_t)gi * FF + c4 * 4);
    float di = dinv[gi];
    float di2 = di * di;
    zs[r][c4 * 4 + 0] = di * s0 + di2 * xv.x;
    zs[r][c4 * 4 + 1] = di * s1 + di2 * xv.y;
    zs[r][c4 * 4 + 2] = di * s2 + di2 * xv.z;
    zs[r][c4 * 4 + 3] = di * s3 + di2 * xv.w;
  }
  __syncthreads();
  const int f = tid & 127;
  const int rg = (tid >> 7) * 8;
  float acc[8] = {0.f, 0.f, 0.f, 0.f, 0.f, 0.f, 0.f, 0.f};
#pragma unroll 4
  for (int k = 0; k < 128; ++k) {
    float wv = w[k * FF + f];
#pragma unroll
    for (int r = 0; r < 8; ++r) acc[r] += zs[rg + r][k] * wv;
  }
#pragma unroll
  for (int r = 0; r < 8; ++r) {
    out[(size_t)(r0 + rg + r) * FF + f] = fmaxf(acc[r], 0.0f);
  }
}

extern "C" void kernel_launch(void* const* d_in, const int* in_sizes, int n_in,
                              void* d_out, int out_size, void* d_ws, size_t ws_size,
                              hipStream_t stream) {
  const float* x   = (const float*)d_in[0];
  const float* adj = (const float*)d_in[1];
  const float* w   = (const float*)d_in[2];
  float* out = (float*)d_out;

  float* dinv  = (float*)d_ws;                                  // 32 KiB @ 0
  short* yT    = (short*)((char*)d_ws + 64 * 1024);             // 2 MiB bf16 [128][8192]
  short* zpart = (short*)((char*)d_ws + 4 * 1024 * 1024);       // 16 MiB bf16 [8][8192][128]

  k_deg    <<<NN,       256, 0, stream>>>(adj, dinv);
  k_scale_t<<<NN / 64,  256, 0, stream>>>(x, dinv, yT);
  k_gemm   <<<128 * KS, 512, 0, stream>>>(adj, yT, zpart);
  k_out    <<<NN / 16,  256, 0, stream>>>(zpart, x, dinv, w, out);
}

// Round 14
// 121.031 us; speedup vs baseline: 1.1200x; 1.1200x over previous
//
#include <hip/hip_runtime.h>
#include <hip/hip_bf16.h>

#define NN 8192
#define FF 128
#define BM 32
#define BK 64
#define KS 8
#define KCH (NN / KS)      // 1024 K per block
#define NSTEP (KCH / BK)   // 16

typedef __attribute__((ext_vector_type(8))) short bf16x8;   // 8 bf16 (4 VGPR)
typedef __attribute__((ext_vector_type(4))) float f32x4;

__device__ __forceinline__ short f2bf(float f) {
  unsigned u = __float_as_uint(f);
  u += 0x7FFFu + ((u >> 16) & 1u);
  return (short)(u >> 16);
}
__device__ __forceinline__ float bf2f(short s) {
  return __uint_as_float(((unsigned)(unsigned short)s) << 16);
}

// async global->LDS DMA, 16B per lane. Dest = wave-uniform LDS base + lane*16.
// Consumes NO VGPRs -> compiler cannot sink it (R9/R10 lesson).
__device__ __forceinline__ void dma16(const void* g, void* lds) {
  __builtin_amdgcn_global_load_lds(
      (const __attribute__((address_space(1))) unsigned int*)(uintptr_t)g,
      (__attribute__((address_space(3))) unsigned int*)(lds),
      16, 0, 0);
}

// packed f32x2 -> bf16x2 (RNE, same results as f2bf), 4 inst per 8 floats
__device__ __forceinline__ bf16x8 cvt8(float4 lo, float4 hi) {
  union { bf16x8 v; unsigned u[4]; } r;
  asm("v_cvt_pk_bf16_f32 %0, %1, %2" : "=v"(r.u[0]) : "v"(lo.x), "v"(lo.y));
  asm("v_cvt_pk_bf16_f32 %0, %1, %2" : "=v"(r.u[1]) : "v"(lo.z), "v"(lo.w));
  asm("v_cvt_pk_bf16_f32 %0, %1, %2" : "=v"(r.u[2]) : "v"(hi.x), "v"(hi.y));
  asm("v_cvt_pk_bf16_f32 %0, %1, %2" : "=v"(r.u[3]) : "v"(hi.z), "v"(hi.w));
  return r.v;
}

// ---- kernel 1: deg[i] = rowsum(adj)+1 ; dinv[i] = (deg+1e-8)^-0.5 ----
__global__ __launch_bounds__(256) void k_deg(const float* __restrict__ adj,
                                             float* __restrict__ dinv) {
  const int row = blockIdx.x;
  const float4* p = (const float4*)(adj + (size_t)row * NN);
  float s = 0.f;
#pragma unroll
  for (int it = 0; it < 8; ++it) {
    float4 v = p[it * 256 + threadIdx.x];
    s += (v.x + v.y) + (v.z + v.w);
  }
#pragma unroll
  for (int off = 32; off > 0; off >>= 1) s += __shfl_down(s, off, 64);
  __shared__ float partial[4];
  if ((threadIdx.x & 63) == 0) partial[threadIdx.x >> 6] = s;
  __syncthreads();
  if (threadIdx.x == 0) {
    float deg = (partial[0] + partial[1]) + (partial[2] + partial[3]) + 1.0f;
    dinv[row] = 1.0f / sqrtf(deg + 1e-8f);
  }
}

// ---- kernel 2: yT[f][i] = dinv[i] * x[i][f]  (bf16, transposed for NT GEMM) ----
__global__ __launch_bounds__(256) void k_scale_t(const float* __restrict__ x,
                                                 const float* __restrict__ dinv,
                                                 short* __restrict__ yT) {
  __shared__ float tile[64][129];
  const int r0 = blockIdx.x * 64;
  const int tid = threadIdx.x;
#pragma unroll
  for (int it = 0; it < 8; ++it) {
    int q = it * 256 + tid;
    int r = q >> 5;
    int c = q & 31;
    float4 v = ((const float4*)(x + (size_t)(r0 + r) * FF))[c];
    float d = dinv[r0 + r];
    tile[r][c * 4 + 0] = v.x * d;
    tile[r][c * 4 + 1] = v.y * d;
    tile[r][c * 4 + 2] = v.z * d;
    tile[r][c * 4 + 3] = v.w * d;
  }
  __syncthreads();
  const int f = tid >> 1;
  const int i0 = (tid & 1) * 32;
#pragma unroll
  for (int g = 0; g < 4; ++g) {
    bf16x8 o;
#pragma unroll
    for (int j = 0; j < 8; ++j) o[j] = f2bf(tile[i0 + g * 8 + j][f]);
    *(bf16x8*)(yT + (size_t)f * NN + r0 + i0 + g * 8) = o;
  }
}

// ---- kernel 3: zpart[ks] = adj[:, ksliced] @ y. DMA MFMA GEMM, 3 gangs/CU. ----
// 2048 blocks (256 M-tiles x 8 K-slices), 256 thr = 4 waves, each wave the
// SAME 32x32 accumulator tile as R12 (bit-identical output). BM=32, BN=128,
// BK=64. LDS = A(8K)+B(16K) dbuf = 48 KB -> THREE blocks/CU (3 independent
// barrier gangs; ledger: gang count is the dominant perf variable). Staging
// is pure DMA (6x dma16/wave, zero VGPRs); A stays f32 in LDS, cvt at
// consume; rule-#21 16B-chunk XOR swizzle (inverse-swizzled global source).
__global__ __launch_bounds__(256) void k_gemm(const float* __restrict__ adj,
                                              const short* __restrict__ yT,
                                              short* __restrict__ zpart) {
  __shared__ float Asf[2][BM * BK];        // 2 x 8 KB, f32, swizzled chunks
  __shared__ short Bsf[2][128 * BK];       // 2 x 16 KB, bf16, swizzled chunks
  const int tid = threadIdx.x;
  const int wave = tid >> 6;
  const int lane = tid & 63;
  const int mb = 255 - (int)(blockIdx.x & 255);   // reverse: read L3-warm rows first
  const int ks = blockIdx.x >> 8;
  const int row0 = mb * BM;
  const size_t kbase = (size_t)ks * KCH;

  // --- DMA source map (inverse-swizzled so linear LDS dest ends up swizzled).
  // A: 32 rows x 16 chunks (16B=4 f32) = 512 chunks; thread covers n=tid,
  //    tid+256. row=n>>4 (i=1: +16, row&7 invariant), logical=(n&15)^(row&7).
  const int rowA = tid >> 4;                       // 0..15
  const int c4l  = (tid & 15) ^ (rowA & 7);
  const float* pa0 = adj + (size_t)(row0 + rowA) * NN + kbase + c4l * 4;
  const float* pa1 = pa0 + (size_t)16 * NN;        // i=1: rows +16
  // B: 128 rows x 8 chunks (16B=8 bf16) = 1024 chunks; n=tid+256i, i=0..3.
  //    row=n>>3 (+32/i, row&7 invariant), logical=(n&7)^(row&7).
  const int rowB = tid >> 3;                       // 0..31
  const int c8l  = (tid & 7) ^ (rowB & 7);
  const short* pb0 = yT + (size_t)rowB * NN + kbase + c8l * 8;

  const int ldsOff = wave * 1024;                  // wave's chunk window (bytes)

#define STAGE_DMA(BUF, koff) do {                                              \
    char* la = (char*)&Asf[BUF][0] + ldsOff;                                   \
    char* lb = (char*)&Bsf[BUF][0] + ldsOff;                                   \
    dma16(pa0 + (koff), la);                                                   \
    dma16(pa1 + (koff), la + 4096);                                            \
    dma16(pb0 + (koff), lb);                                                   \
    dma16(pb0 + (size_t)32 * NN + (koff), lb + 4096);                          \
    dma16(pb0 + (size_t)64 * NN + (koff), lb + 8192);                          \
    dma16(pb0 + (size_t)96 * NN + (koff), lb + 12288);                         \
  } while (0)

  // --- compute-side fragment map (proven MFMA layout, swizzled addresses)
  const int wn = wave * 32;          // 0/32/64/96
  const int fr = lane & 15;
  const int kh = (lane >> 4) * 8;
  const int khq = kh >> 2;           // A chunk sub-offset (f32 16B chunks)
  const int kh8 = kh >> 3;           // B chunk sub-offset
  const int sw  = fr & 7;            // row swizzle (wn/16 are 0 mod 8... wn mult of 32)
  const int ra0 = fr, ra1 = fr + 16;
  const int rb0 = wn + fr, rb1 = rb0 + 16;

  f32x4 acc00 = {0.f,0.f,0.f,0.f}, acc01 = acc00, acc10 = acc00, acc11 = acc00;

#define COMPUTE(BUF) do {                                                      \
    const char* Ab = (const char*)&Asf[BUF][0];                                \
    const char* Bb = (const char*)&Bsf[BUF][0];                                \
    _Pragma("unroll")                                                          \
    for (int kk = 0; kk < 2; ++kk) {                                           \
      int c4 = kk * 8 + khq;                                                   \
      int c8 = kk * 4 + kh8;                                                   \
      float4 lo0 = *(const float4*)(Ab + ra0 * 256 + (((c4    ) ^ sw) << 4));  \
      float4 hi0 = *(const float4*)(Ab + ra0 * 256 + (((c4 + 1) ^ sw) << 4));  \
      float4 lo1 = *(const float4*)(Ab + ra1 * 256 + (((c4    ) ^ sw) << 4));  \
      float4 hi1 = *(const float4*)(Ab + ra1 * 256 + (((c4 + 1) ^ sw) << 4));  \
      bf16x8 b0 = *(const bf16x8*)(Bb + rb0 * 128 + ((c8 ^ sw) << 4));         \
      bf16x8 b1 = *(const bf16x8*)(Bb + rb1 * 128 + ((c8 ^ sw) << 4));         \
      bf16x8 a0 = cvt8(lo0, hi0);                                              \
      bf16x8 a1 = cvt8(lo1, hi1);                                              \
      acc00 = __builtin_amdgcn_mfma_f32_16x16x32_bf16(a0, b0, acc00, 0, 0, 0); \
      acc01 = __builtin_amdgcn_mfma_f32_16x16x32_bf16(a0, b1, acc01, 0, 0, 0); \
      acc10 = __builtin_amdgcn_mfma_f32_16x16x32_bf16(a1, b0, acc10, 0, 0, 0); \
      acc11 = __builtin_amdgcn_mfma_f32_16x16x32_bf16(a1, b1, acc11, 0, 0, 0); \
    }                                                                          \
  } while (0)

  // prologue: DMA tile 0 -> buf0; drain; then steady 2-phase (R12 schedule)
  STAGE_DMA(0, 0);
  __syncthreads();

  int buf = 0;
  for (int t = 0; t < NSTEP; ++t) {
    if (t + 1 < NSTEP) STAGE_DMA(buf ^ 1, (t + 1) * BK);
    __builtin_amdgcn_sched_barrier(0);   // pin: DMA issues before compute
    COMPUTE(buf);
    __syncthreads();                     // readers of buf done + DMA landed
    buf ^= 1;
  }

  // epilogue: D layout col=lane&15, row=(lane>>4)*4+r ; store bf16 partials
  const int r4 = (lane >> 4) * 4;
  short* zp = zpart + ((size_t)ks << 20);   // slice stride 8192*128
#pragma unroll
  for (int r = 0; r < 4; ++r) {
    int gi0 = row0 + r4 + r;
    int gi1 = gi0 + 16;
    zp[(size_t)gi0 * FF + wn + fr]      = f2bf(acc00[r]);
    zp[(size_t)gi0 * FF + wn + 16 + fr] = f2bf(acc01[r]);
    zp[(size_t)gi1 * FF + wn + fr]      = f2bf(acc10[r]);
    zp[(size_t)gi1 * FF + wn + 16 + fr] = f2bf(acc11[r]);
  }
#undef STAGE_DMA
#undef COMPUTE
}

// ---- kernel 4: out = relu((dinv*(sum_ks zpart + dinv*x)) @ W) ----
__global__ __launch_bounds__(256) void k_out(const short* __restrict__ zpart,
                                             const float* __restrict__ x,
                                             const float* __restrict__ dinv,
                                             const float* __restrict__ w,
                                             float* __restrict__ out) {
  __shared__ float zs[16][128];
  const int r0 = blockIdx.x * 16;
  const int tid = threadIdx.x;
#pragma unroll
  for (int half = 0; half < 2; ++half) {
    int p = half * 256 + tid;
    int r = p >> 5;
    int c4 = p & 31;
    int gi = r0 + r;
    const short* base = zpart + (size_t)gi * FF + c4 * 4;
    float s0 = 0.f, s1 = 0.f, s2 = 0.f, s3 = 0.f;
#pragma unroll
    for (int sidx = 0; sidx < KS; ++sidx) {
      short4 v = *(const short4*)(base + ((size_t)sidx << 20));
      s0 += bf2f(v.x); s1 += bf2f(v.y); s2 += bf2f(v.z); s3 += bf2f(v.w);
    }
    float4 xv = *(const float4*)(x + (size_t)gi * FF + c4 * 4);
    float di = dinv[gi];
    float di2 = di * di;
    zs[r][c4 * 4 + 0] = di * s0 + di2 * xv.x;
    zs[r][c4 * 4 + 1] = di * s1 + di2 * xv.y;
    zs[r][c4 * 4 + 2] = di * s2 + di2 * xv.z;
    zs[r][c4 * 4 + 3] = di * s3 + di2 * xv.w;
  }
  __syncthreads();
  const int f = tid & 127;
  const int rg = (tid >> 7) * 8;
  float acc[8] = {0.f, 0.f, 0.f, 0.f, 0.f, 0.f, 0.f, 0.f};
#pragma unroll 4
  for (int k = 0; k < 128; ++k) {
    float wv = w[k * FF + f];
#pragma unroll
    for (int r = 0; r < 8; ++r) acc[r] += zs[rg + r][k] * wv;
  }
#pragma unroll
  for (int r = 0; r < 8; ++r) {
    out[(size_t)(r0 + rg + r) * FF + f] = fmaxf(acc[r], 0.0f);
  }
}

extern "C" void kernel_launch(void* const* d_in, const int* in_sizes, int n_in,
                              void* d_out, int out_size, void* d_ws, size_t ws_size,
                              hipStream_t stream) {
  const float* x   = (const float*)d_in[0];
  const float* adj = (const float*)d_in[1];
  const float* w   = (const float*)d_in[2];
  float* out = (float*)d_out;

  float* dinv  = (float*)d_ws;                                  // 32 KiB @ 0
  short* yT    = (short*)((char*)d_ws + 64 * 1024);             // 2 MiB bf16 [128][8192]
  short* zpart = (short*)((char*)d_ws + 4 * 1024 * 1024);       // 16 MiB bf16 [8][8192][128]

  k_deg    <<<NN,       256, 0, stream>>>(adj, dinv);
  k_scale_t<<<NN / 64,  256, 0, stream>>>(x, dinv, yT);
  k_gemm   <<<256 * KS, 256, 0, stream>>>(adj, yT, zpart);
  k_out    <<<NN / 16,  256, 0, stream>>>(zpart, x, dinv, w, out);
}

// Round 15
// 113.236 us; speedup vs baseline: 1.1971x; 1.0688x over previous
//
#include <hip/hip_runtime.h>
#include <hip/hip_bf16.h>

#define NN 8192
#define FF 128
#define BM 64
#define BK 64
#define KS 8
#define KCH (NN / KS)      // 1024 K per block
#define NSTEP (KCH / BK)   // 16

typedef __attribute__((ext_vector_type(8))) short bf16x8;   // 8 bf16 (4 VGPR)
typedef __attribute__((ext_vector_type(4))) float f32x4;

__device__ __forceinline__ short f2bf(float f) {
  unsigned u = __float_as_uint(f);
  u += 0x7FFFu + ((u >> 16) & 1u);
  return (short)(u >> 16);
}
__device__ __forceinline__ float bf2f(short s) {
  return __uint_as_float(((unsigned)(unsigned short)s) << 16);
}

// async global->LDS DMA, 16B per lane. Dest = wave-uniform LDS base + lane*16.
// Consumes NO VGPRs -> the compiler cannot sink it for register pressure
// (R9/R10 post-mortem: reg-staged prefetch always got sunk to its consumer).
__device__ __forceinline__ void dma16(const void* g, void* lds) {
  __builtin_amdgcn_global_load_lds(
      (const __attribute__((address_space(1))) unsigned int*)(uintptr_t)g,
      (__attribute__((address_space(3))) unsigned int*)(lds),
      16, 0, 0);
}

// packed f32x2 -> bf16x2 (RNE, same results as f2bf), 4 inst per 8 floats
__device__ __forceinline__ bf16x8 cvt8(float4 lo, float4 hi) {
  union { bf16x8 v; unsigned u[4]; } r;
  asm("v_cvt_pk_bf16_f32 %0, %1, %2" : "=v"(r.u[0]) : "v"(lo.x), "v"(lo.y));
  asm("v_cvt_pk_bf16_f32 %0, %1, %2" : "=v"(r.u[1]) : "v"(lo.z), "v"(lo.w));
  asm("v_cvt_pk_bf16_f32 %0, %1, %2" : "=v"(r.u[2]) : "v"(hi.x), "v"(hi.y));
  asm("v_cvt_pk_bf16_f32 %0, %1, %2" : "=v"(r.u[3]) : "v"(hi.z), "v"(hi.w));
  return r.v;
}

// ---- kernel 1: deg[i] = rowsum(adj)+1 ; dinv[i] = (deg+1e-8)^-0.5 ----
__global__ __launch_bounds__(256) void k_deg(const float* __restrict__ adj,
                                             float* __restrict__ dinv) {
  const int row = blockIdx.x;
  const float4* p = (const float4*)(adj + (size_t)row * NN);
  float s = 0.f;
#pragma unroll
  for (int it = 0; it < 8; ++it) {
    float4 v = p[it * 256 + threadIdx.x];
    s += (v.x + v.y) + (v.z + v.w);
  }
#pragma unroll
  for (int off = 32; off > 0; off >>= 1) s += __shfl_down(s, off, 64);
  __shared__ float partial[4];
  if ((threadIdx.x & 63) == 0) partial[threadIdx.x >> 6] = s;
  __syncthreads();
  if (threadIdx.x == 0) {
    float deg = (partial[0] + partial[1]) + (partial[2] + partial[3]) + 1.0f;
    dinv[row] = 1.0f / sqrtf(deg + 1e-8f);
  }
}

// ---- kernel 2: yT[f][i] = dinv[i] * x[i][f]  (bf16, transposed for NT GEMM) ----
__global__ __launch_bounds__(256) void k_scale_t(const float* __restrict__ x,
                                                 const float* __restrict__ dinv,
                                                 short* __restrict__ yT) {
  __shared__ float tile[64][129];
  const int r0 = blockIdx.x * 64;
  const int tid = threadIdx.x;
#pragma unroll
  for (int it = 0; it < 8; ++it) {
    int q = it * 256 + tid;
    int r = q >> 5;
    int c = q & 31;
    float4 v = ((const float4*)(x + (size_t)(r0 + r) * FF))[c];
    float d = dinv[r0 + r];
    tile[r][c * 4 + 0] = v.x * d;
    tile[r][c * 4 + 1] = v.y * d;
    tile[r][c * 4 + 2] = v.z * d;
    tile[r][c * 4 + 3] = v.w * d;
  }
  __syncthreads();
  const int f = tid >> 1;
  const int i0 = (tid & 1) * 32;
#pragma unroll
  for (int g = 0; g < 4; ++g) {
    bf16x8 o;
#pragma unroll
    for (int j = 0; j < 8; ++j) o[j] = f2bf(tile[i0 + g * 8 + j][f]);
    *(bf16x8*)(yT + (size_t)f * NN + r0 + i0 + g * 8) = o;
  }
}

// ---- kernel 3: zpart[ks] = adj[:, ksliced] @ y. gload_lds MFMA GEMM. ----
// BEST CONFIG (R12, 112.85 us). 1024 blocks (128 M-tiles x 8 K-slices),
// 512 thr = 8 waves (2M x 4N), BM=64, BN=128, BK=64, LDS 64 KB -> 2 gangs/CU
// (gang count = the dominant variable: 1 gang 135us, 2 gangs 112.9, 3 small
// gangs 121). Staging is pure DMA (zero VGPRs -> unsinkable); A stays f32 in
// LDS, cvt to bf16 at consume (v_cvt_pk_bf16_f32, RNE); rule-#21 16B-chunk
// XOR swizzle (inverse-swizzled global source + swizzled LDS read).
__global__ __launch_bounds__(512) void k_gemm(const float* __restrict__ adj,
                                              const short* __restrict__ yT,
                                              short* __restrict__ zpart) {
  __shared__ float Asf[2][BM * BK];        // 2 x 16 KB, f32, swizzled chunks
  __shared__ short Bsf[2][128 * BK];       // 2 x 16 KB, bf16, swizzled chunks
  const int tid = threadIdx.x;
  const int wave = tid >> 6;
  const int lane = tid & 63;
  const int mb = 127 - (int)(blockIdx.x & 127);   // reverse: read L3-warm rows first
  const int ks = blockIdx.x >> 7;
  const int row0 = mb * BM;
  const size_t kbase = (size_t)ks * KCH;

  // --- DMA source map (inverse-swizzled so linear LDS dest ends up swizzled).
  const int rowA = tid >> 4;                       // 0..31
  const int c4l  = (tid & 15) ^ (rowA & 7);
  const float* pa0 = adj + (size_t)(row0 + rowA) * NN + kbase + c4l * 4;
  const float* pa1 = pa0 + (size_t)32 * NN;        // rows +32
  const int rowB = tid >> 3;                       // 0..63
  const int c8l  = (tid & 7) ^ (rowB & 7);
  const short* pb0 = yT + (size_t)rowB * NN + kbase + c8l * 8;
  const short* pb1 = pb0 + (size_t)64 * NN;        // rows +64

  const int ldsOff = wave * 1024;                  // wave's chunk window (bytes)

#define STAGE_DMA(BUF, koff) do {                                              \
    char* la = (char*)&Asf[BUF][0] + ldsOff;                                   \
    char* lb = (char*)&Bsf[BUF][0] + ldsOff;                                   \
    dma16(pa0 + (koff), la);                                                   \
    dma16(pa1 + (koff), la + 8192);                                            \
    dma16(pb0 + (koff), lb);                                                   \
    dma16(pb1 + (koff), lb + 8192);                                            \
  } while (0)

  // --- compute-side fragment map (proven MFMA layout, swizzled addresses)
  const int wm = (wave >> 2) * 32;   // 0/32
  const int wn = (wave & 3) * 32;    // 0/32/64/96
  const int fr = lane & 15;
  const int kh = (lane >> 4) * 8;
  const int khq = kh >> 2;           // A chunk sub-offset (f32 16B chunks)
  const int kh8 = kh >> 3;           // B chunk sub-offset
  const int sw  = fr & 7;            // row swizzle (wm/wn/16 are 0 mod 8)
  const int ra0 = wm + fr, ra1 = ra0 + 16;
  const int rb0 = wn + fr, rb1 = rb0 + 16;

  f32x4 acc00 = {0.f,0.f,0.f,0.f}, acc01 = acc00, acc10 = acc00, acc11 = acc00;

#define COMPUTE(BUF) do {                                                      \
    const char* Ab = (const char*)&Asf[BUF][0];                                \
    const char* Bb = (const char*)&Bsf[BUF][0];                                \
    _Pragma("unroll")                                                          \
    for (int kk = 0; kk < 2; ++kk) {                                           \
      int c4 = kk * 8 + khq;                                                   \
      int c8 = kk * 4 + kh8;                                                   \
      float4 lo0 = *(const float4*)(Ab + ra0 * 256 + (((c4    ) ^ sw) << 4));  \
      float4 hi0 = *(const float4*)(Ab + ra0 * 256 + (((c4 + 1) ^ sw) << 4));  \
      float4 lo1 = *(const float4*)(Ab + ra1 * 256 + (((c4    ) ^ sw) << 4));  \
      float4 hi1 = *(const float4*)(Ab + ra1 * 256 + (((c4 + 1) ^ sw) << 4));  \
      bf16x8 b0 = *(const bf16x8*)(Bb + rb0 * 128 + ((c8 ^ sw) << 4));         \
      bf16x8 b1 = *(const bf16x8*)(Bb + rb1 * 128 + ((c8 ^ sw) << 4));         \
      bf16x8 a0 = cvt8(lo0, hi0);                                              \
      bf16x8 a1 = cvt8(lo1, hi1);                                              \
      acc00 = __builtin_amdgcn_mfma_f32_16x16x32_bf16(a0, b0, acc00, 0, 0, 0); \
      acc01 = __builtin_amdgcn_mfma_f32_16x16x32_bf16(a0, b1, acc01, 0, 0, 0); \
      acc10 = __builtin_amdgcn_mfma_f32_16x16x32_bf16(a1, b0, acc10, 0, 0, 0); \
      acc11 = __builtin_amdgcn_mfma_f32_16x16x32_bf16(a1, b1, acc11, 0, 0, 0); \
    }                                                                          \
  } while (0)

  // prologue: DMA tile 0 -> buf0; drain; then steady 2-phase
  STAGE_DMA(0, 0);
  __syncthreads();

  int buf = 0;
  for (int t = 0; t < NSTEP; ++t) {
    if (t + 1 < NSTEP) STAGE_DMA(buf ^ 1, (t + 1) * BK);
    __builtin_amdgcn_sched_barrier(0);   // pin: DMA issues before compute
    COMPUTE(buf);
    __syncthreads();                     // readers of buf done + DMA landed
    buf ^= 1;
  }

  // epilogue: D layout col=lane&15, row=(lane>>4)*4+r ; store bf16 partials
  const int r4 = (lane >> 4) * 4;
  short* zp = zpart + ((size_t)ks << 20);   // slice stride 8192*128
#pragma unroll
  for (int r = 0; r < 4; ++r) {
    int gi0 = row0 + wm + r4 + r;
    int gi1 = gi0 + 16;
    zp[(size_t)gi0 * FF + wn + fr]      = f2bf(acc00[r]);
    zp[(size_t)gi0 * FF + wn + 16 + fr] = f2bf(acc01[r]);
    zp[(size_t)gi1 * FF + wn + fr]      = f2bf(acc10[r]);
    zp[(size_t)gi1 * FF + wn + 16 + fr] = f2bf(acc11[r]);
  }
#undef STAGE_DMA
#undef COMPUTE
}

// ---- kernel 4: out = relu((dinv*(sum_ks zpart + dinv*x)) @ W) ----
__global__ __launch_bounds__(256) void k_out(const short* __restrict__ zpart,
                                             const float* __restrict__ x,
                                             const float* __restrict__ dinv,
                                             const float* __restrict__ w,
                                             float* __restrict__ out) {
  __shared__ float zs[16][128];
  const int r0 = blockIdx.x * 16;
  const int tid = threadIdx.x;
#pragma unroll
  for (int half = 0; half < 2; ++half) {
    int p = half * 256 + tid;
    int r = p >> 5;
    int c4 = p & 31;
    int gi = r0 + r;
    const short* base = zpart + (size_t)gi * FF + c4 * 4;
    float s0 = 0.f, s1 = 0.f, s2 = 0.f, s3 = 0.f;
#pragma unroll
    for (int sidx = 0; sidx < KS; ++sidx) {
      short4 v = *(const short4*)(base + ((size_t)sidx << 20));
      s0 += bf2f(v.x); s1 += bf2f(v.y); s2 += bf2f(v.z); s3 += bf2f(v.w);
    }
    float4 xv = *(const float4*)(x + (size_t)gi * FF + c4 * 4);
    float di = dinv[gi];
    float di2 = di * di;
    zs[r][c4 * 4 + 0] = di * s0 + di2 * xv.x;
    zs[r][c4 * 4 + 1] = di * s1 + di2 * xv.y;
    zs[r][c4 * 4 + 2] = di * s2 + di2 * xv.z;
    zs[r][c4 * 4 + 3] = di * s3 + di2 * xv.w;
  }
  __syncthreads();
  const int f = tid & 127;
  const int rg = (tid >> 7) * 8;
  float acc[8] = {0.f, 0.f, 0.f, 0.f, 0.f, 0.f, 0.f, 0.f};
#pragma unroll 4
  for (int k = 0; k < 128; ++k) {
    float wv = w[k * FF + f];
#pragma unroll
    for (int r = 0; r < 8; ++r) acc[r] += zs[rg + r][k] * wv;
  }
#pragma unroll
  for (int r = 0; r < 8; ++r) {
    out[(size_t)(r0 + rg + r) * FF + f] = fmaxf(acc[r], 0.0f);
  }
}

extern "C" void kernel_launch(void* const* d_in, const int* in_sizes, int n_in,
                              void* d_out, int out_size, void* d_ws, size_t ws_size,
                              hipStream_t stream) {
  const float* x   = (const float*)d_in[0];
  const float* adj = (const float*)d_in[1];
  const float* w   = (const float*)d_in[2];
  float* out = (float*)d_out;

  float* dinv  = (float*)d_ws;                                  // 32 KiB @ 0
  short* yT    = (short*)((char*)d_ws + 64 * 1024);             // 2 MiB bf16 [128][8192]
  short* zpart = (short*)((char*)d_ws + 4 * 1024 * 1024);       // 16 MiB bf16 [8][8192][128]

  k_deg    <<<NN,       256, 0, stream>>>(adj, dinv);
  k_scale_t<<<NN / 64,  256, 0, stream>>>(x, dinv, yT);
  k_gemm   <<<128 * KS, 512, 0, stream>>>(adj, yT, zpart);
  k_out    <<<NN / 16,  256, 0, stream>>>(zpart, x, dinv, w, out);
}